// Round 1
// 324.131 us; speedup vs baseline: 1.0386x; 1.0386x over previous
//
#include <hip/hip_runtime.h>

#define BB 64
#define TT 2000
#define DENC 512
#define IDIM 512
#define HID 256
#define KK 10

// ---------------------------------------------------------------------------
// Single fused kernel, one block per batch element b (64 blocks x 256 thr).
//
// Phase A: h = tanh(W1 @ state + b1)       (thread t owns h[t])
// Phase B: z_o = W2[o] @ h + b2[o], o = 3k / 3k+1 only (softmax over the
//          singleton N axis makes weights == 1 exactly, so 3k+2 is dead).
//          Parallelized: 20 outputs x 8 lanes, shuffle-reduced (replaces the
//          old serial 20-thread 256-length dot).
//          s_ms[2k] = exp(z_3k) = mean_k, s_ms[2k+1] = exp(-z_{3k+1}) = 1/scale_k
// Phase C: align[j] = sum_k sig((j+.5-m)/s) - sig((j-.5-m)/s); written to out
//          and to LDS; rows with |align| > 1e-8 compacted into s_rows
//          (identical skip criterion to the previous 3-kernel version).
// Phase D: context[d] = sum_{active j} align[j] * enc[b,j,d]; active rows
//          split across the 4 waves (lane owns 8 d's), LDS combine at end.
//          No atomics, no separate zero-init (block owns b entirely).
//
// Rationale: timed region is dominated by two harness 1000-MiB poison fills
// (~318 us at 81-84% HBM peak, outside kernel control); this fusion attacks
// the remaining ~18 us: 2 launch gaps, serial W2 phase, 6400-block ctx
// dispatch overhead.
// ---------------------------------------------------------------------------
__global__ __launch_bounds__(256)
void fused_kernel(const float* __restrict__ state,
                  const float* __restrict__ enc,
                  const float* __restrict__ W1,
                  const float* __restrict__ b1,
                  const float* __restrict__ W2,
                  const float* __restrict__ b2,
                  float* __restrict__ out /* [BB*DENC ctx][BB*TT align] */) {
    __shared__ __align__(16) float s_state[IDIM];
    __shared__ __align__(16) float s_h[HID];
    __shared__ float s_ms[2 * KK];
    __shared__ __align__(16) float s_align[TT];
    __shared__ int   s_rows[TT];
    __shared__ int   s_cnt;
    __shared__ __align__(16) float s_part[4][DENC];

    const int b = blockIdx.x;
    const int t = threadIdx.x;

    if (t == 0) s_cnt = 0;
    const float* st = state + (size_t)b * IDIM;
    s_state[t]       = st[t];
    s_state[t + 256] = st[t + 256];
    __syncthreads();

    // ---- Phase A: h[t] = tanh(b1[t] + dot(W1[t,:], state)) ----
    {
        const float* w1r = W1 + (size_t)t * IDIM;
        float sum = 0.f;
#pragma unroll 8
        for (int k = 0; k < IDIM; k += 4) {
            float4 w = *(const float4*)(w1r + k);
            float4 s = *(const float4*)(s_state + k);
            sum += w.x * s.x + w.y * s.y + w.z * s.z + w.w * s.w;
        }
        s_h[t] = tanhf(sum + b1[t]);
    }
    __syncthreads();

    // ---- Phase B: 20 outputs, 8 lanes each, shuffle-reduce ----
    if (t < 8 * 2 * KK) {
        const int g = t >> 3;        // group 0..19  (== old thread index)
        const int l = t & 7;
        const int k = g >> 1;
        const int which = g & 1;     // 0 -> mean, 1 -> scale
        const int o = 3 * k + which;
        const float* w2r = W2 + o * HID;
        float z = 0.f;
#pragma unroll
        for (int i = 0; i < HID / 8; ++i) {
            const int idx = l + 8 * i;     // lanes consecutive: coalesced W2,
            z += w2r[idx] * s_h[idx];      // conflict-free s_h banks
        }
        z += __shfl_down(z, 4, 8);
        z += __shfl_down(z, 2, 8);
        z += __shfl_down(z, 1, 8);
        if (l == 0) {
            z += b2[o];
            s_ms[g] = (which == 0) ? expf(z) : expf(-z);
        }
    }
    __syncthreads();

    // ---- Phase C: align + active-row compaction ----
    float mean[KK], invs[KK];
#pragma unroll
    for (int kk = 0; kk < KK; ++kk) {
        mean[kk] = s_ms[2 * kk];
        invs[kk] = s_ms[2 * kk + 1];
    }
    float* align_out = out + BB * DENC + (size_t)b * TT;
    for (int j = t; j < TT; j += 256) {
        const float fj = (float)j;
        float a = 0.f;
#pragma unroll
        for (int kk = 0; kk < KK; ++kk) {
            const float x1 = (fj + 0.5f - mean[kk]) * invs[kk];
            const float x2 = (fj - 0.5f - mean[kk]) * invs[kk];
            a += 1.f / (1.f + expf(-x1)) - 1.f / (1.f + expf(-x2));
        }
        s_align[j] = a;
        align_out[j] = a;
        if (fabsf(a) > 1e-8f) {            // same skip bound as before:
            const int idx = atomicAdd(&s_cnt, 1);   // 2000*1e-8*max|enc| ~ 1e-4
            s_rows[idx] = j;
        }
    }
    __syncthreads();

    // ---- Phase D: context over active rows, 4-wave split ----
    const int n  = s_cnt;
    const int w  = t >> 6;        // wave 0..3
    const int l  = t & 63;        // lane
    const int d0 = l * 8;         // lane owns d0..d0+7
    const float* ebase = enc + (size_t)b * TT * DENC;
    float4 acc0 = make_float4(0.f, 0.f, 0.f, 0.f);
    float4 acc1 = make_float4(0.f, 0.f, 0.f, 0.f);
    for (int r = w; r < n; r += 4) {
        const int j = s_rows[r];
        const float a = s_align[j];
        const float* row = ebase + (size_t)j * DENC + d0;
        const float4 v0 = *(const float4*)(row);
        const float4 v1 = *(const float4*)(row + 4);
        acc0.x += a * v0.x; acc0.y += a * v0.y;
        acc0.z += a * v0.z; acc0.w += a * v0.w;
        acc1.x += a * v1.x; acc1.y += a * v1.y;
        acc1.z += a * v1.z; acc1.w += a * v1.w;
    }
    *(float4*)&s_part[w][d0]     = acc0;   // every wave writes (zeros if idle)
    *(float4*)&s_part[w][d0 + 4] = acc1;
    __syncthreads();

    {
        const int d = t * 2;                        // 256 thr x 2 d's = 512
        const float2 r0 = *(const float2*)&s_part[0][d];
        const float2 r1 = *(const float2*)&s_part[1][d];
        const float2 r2 = *(const float2*)&s_part[2][d];
        const float2 r3 = *(const float2*)&s_part[3][d];
        float2 c;
        c.x = (r0.x + r1.x) + (r2.x + r3.x);
        c.y = (r0.y + r1.y) + (r2.y + r3.y);
        *(float2*)(out + (size_t)b * DENC + d) = c;
    }
}

extern "C" void kernel_launch(void* const* d_in, const int* in_sizes, int n_in,
                              void* d_out, int out_size, void* d_ws, size_t ws_size,
                              hipStream_t stream) {
    const float* state = (const float*)d_in[0];
    const float* enc_z = (const float*)d_in[1];
    const float* W1    = (const float*)d_in[2];
    const float* b1    = (const float*)d_in[3];
    const float* W2    = (const float*)d_in[4];
    const float* b2    = (const float*)d_in[5];
    float* out = (float*)d_out;
    (void)d_ws; (void)ws_size;

    fused_kernel<<<BB, 256, 0, stream>>>(state, enc_z, W1, b1, W2, b2, out);
}